// Round 4
// baseline (1635.928 us; speedup 1.0000x reference)
//
#include <hip/hip_runtime.h>

#define NN 50000
#define NE 800000
#define DD 64
#define NL 5
#define NG 256
#define NC 10
#define BN_EPS 1e-5f
#define NCHUNK ((NN + 255) / 256)   // 196
#define WT 68   // transposed-W k-stride: 68 floats = 17 x 16B -> b128 conflict-free

// Pack two floats as bf16 (RNE) into one uint: low16 = q, high16 = v.
__device__ inline unsigned int pack_bf16x2(float q, float v) {
    unsigned int uq = __float_as_uint(q);
    unsigned int uv = __float_as_uint(v);
    uq += 0x7FFFu + ((uq >> 16) & 1u);
    uv += 0x7FFFu + ((uv >> 16) & 1u);
    return (uv & 0xFFFF0000u) | (uq >> 16);
}

__device__ inline float sigmoidf_fast(float x) {
    return 1.f / (1.f + __expf(-x));
}

// ---------------------------------------------------------------------------
// Fused 4-matrix GEMM with folded BN of the PREVIOUS layer.
// W staged TRANSPOSED in LDS ([c][k], stride WT=68 -> conflict-free b128);
// X tile read as broadcast float4. Inner loop: 12 b128 LDS reads / 128 fmas.
// In-place safe (Hin == OUT): block stages its 32 rows to LDS before writing.
// ---------------------------------------------------------------------------
__global__ __launch_bounds__(256) void gemm4_kernel(
    const float* Hin,
    const float* __restrict__ Wk, const float* __restrict__ Wq,
    const float* __restrict__ Wv, const float* __restrict__ Ws,
    const float* __restrict__ bk, const float* __restrict__ bq,
    const float* __restrict__ bv, const float* __restrict__ bs,
    const float* __restrict__ prevStats,   // 128 floats (sum, sumsq) or null
    const float* __restrict__ prevGamma, const float* __restrict__ prevBeta,
    float* __restrict__ K, unsigned int* __restrict__ QVp, float* OUT)
{
    __shared__ float sWt[4][64 * WT];   // [mat][c*WT + k]
    __shared__ float sX[32 * 64];
    __shared__ float sA[64], sB[64];
    const int tid = threadIdx.x;

    if (tid < 64) {
        float a = 1.f, b = 0.f;
        if (prevStats) {
            const float invN = 1.0f / (float)NN;
            const float mean = prevStats[tid] * invN;
            const float var  = prevStats[64 + tid] * invN - mean * mean;
            const float inv  = rsqrtf(var + BN_EPS);
            a = inv * prevGamma[tid];
            b = prevBeta[tid] - mean * a;
        }
        sA[tid] = a;
        sB[tid] = b;
    }

    // Stage W transposed: W[k*64+c] -> sWt[m][c*WT+k]
    for (int i = tid; i < 4096; i += 256) {
        const int k = i >> 6, cc = i & 63;
        sWt[0][cc * WT + k] = Wk[i];
        sWt[1][cc * WT + k] = Wq[i];
        sWt[2][cc * WT + k] = Wv[i];
        sWt[3][cc * WT + k] = Ws[i];
    }

    const int row0 = blockIdx.x * 32;
    float4* sX4 = (float4*)sX;
    const float4* Hin4 = (const float4*)(Hin + (size_t)row0 * DD);
    for (int i = tid; i < 32 * 16; i += 256) {
        int r = row0 + (i >> 4);
        sX4[i] = (r < NN) ? Hin4[i] : make_float4(0.f, 0.f, 0.f, 0.f);
    }
    __syncthreads();

    if (prevStats) {
        for (int i = tid; i < 32 * 64; i += 256)
            sX[i] = fmaf(sX[i], sA[i & 63], sB[i & 63]);
        __syncthreads();
    }

    const int c  = tid & 63;
    const int rg = tid >> 6;

    float accK[8], accQ[8], accV[8], accS[8];
#pragma unroll
    for (int j = 0; j < 8; j++) { accK[j] = accQ[j] = accV[j] = accS[j] = 0.f; }

    const float4* wK4 = (const float4*)(&sWt[0][c * WT]);
    const float4* wQ4 = (const float4*)(&sWt[1][c * WT]);
    const float4* wV4 = (const float4*)(&sWt[2][c * WT]);
    const float4* wS4 = (const float4*)(&sWt[3][c * WT]);

#pragma unroll
    for (int kg = 0; kg < 16; kg++) {
        const float4 wk4 = wK4[kg];
        const float4 wq4 = wQ4[kg];
        const float4 wv4 = wV4[kg];
        const float4 ws4 = wS4[kg];
#pragma unroll
        for (int j = 0; j < 8; j++) {
            const float4 x4 = *(const float4*)(&sX[(rg * 8 + j) * 64 + kg * 4]);
            accK[j] = fmaf(x4.x, wk4.x, fmaf(x4.y, wk4.y, fmaf(x4.z, wk4.z, fmaf(x4.w, wk4.w, accK[j]))));
            accQ[j] = fmaf(x4.x, wq4.x, fmaf(x4.y, wq4.y, fmaf(x4.z, wq4.z, fmaf(x4.w, wq4.w, accQ[j]))));
            accV[j] = fmaf(x4.x, wv4.x, fmaf(x4.y, wv4.y, fmaf(x4.z, wv4.z, fmaf(x4.w, wv4.w, accV[j]))));
            accS[j] = fmaf(x4.x, ws4.x, fmaf(x4.y, ws4.y, fmaf(x4.z, ws4.z, fmaf(x4.w, ws4.w, accS[j]))));
        }
    }

    const float bkc = bk[c], bqc = bq[c], bvc = bv[c], bsc = bs[c];
#pragma unroll
    for (int j = 0; j < 8; j++) {
        const int r = row0 + rg * 8 + j;
        if (r < NN) {
            K[(size_t)r * DD + c]   = accK[j] + bkc;
            QVp[(size_t)r * DD + c] = pack_bf16x2(accQ[j] + bqc, accV[j] + bvc);
            OUT[(size_t)r * DD + c] = accS[j] + bsc;
        }
    }
}

// ---------------------------------------------------------------------------
// CSR build: histogram of dst, two-level exclusive scan, scatter fill.
// ---------------------------------------------------------------------------
__global__ __launch_bounds__(256) void deg_kernel(
    const int* __restrict__ ei, int* __restrict__ deg)
{
    const int e = blockIdx.x * 256 + threadIdx.x;
    if (e < NE) atomicAdd(&deg[ei[NE + e]], 1);
}

__global__ __launch_bounds__(256) void scan_partial_kernel(
    const int* __restrict__ deg, int* __restrict__ psums)
{
    __shared__ int ls[256];
    const int i = blockIdx.x * 256 + threadIdx.x;
    ls[threadIdx.x] = (i < NN) ? deg[i] : 0;
    __syncthreads();
    for (int off = 128; off > 0; off >>= 1) {
        if (threadIdx.x < off) ls[threadIdx.x] += ls[threadIdx.x + off];
        __syncthreads();
    }
    if (threadIdx.x == 0) psums[blockIdx.x] = ls[0];
}

__global__ void scan_offsets_kernel(int* __restrict__ psums, int* __restrict__ rowst)
{
    if (threadIdx.x == 0) {
        int running = 0;
        for (int i = 0; i < NCHUNK; i++) {
            int t = psums[i];
            psums[i] = running;
            running += t;
        }
        rowst[NN] = running;  // == NE
    }
}

__global__ __launch_bounds__(256) void scan_final_kernel(
    const int* __restrict__ deg, const int* __restrict__ psums,
    int* __restrict__ rowst, int* __restrict__ cursor)
{
    __shared__ int ls[256];
    const int i = blockIdx.x * 256 + threadIdx.x;
    const int x = (i < NN) ? deg[i] : 0;
    ls[threadIdx.x] = x;
    __syncthreads();
    for (int off = 1; off < 256; off <<= 1) {
        int v = (threadIdx.x >= off) ? ls[threadIdx.x - off] : 0;
        __syncthreads();
        ls[threadIdx.x] += v;
        __syncthreads();
    }
    if (i < NN) {
        const int excl = psums[blockIdx.x] + ls[threadIdx.x] - x;
        rowst[i]  = excl;
        cursor[i] = excl;
    }
}

__global__ __launch_bounds__(256) void fill_kernel(
    const int* __restrict__ ei, int* __restrict__ cursor, int* __restrict__ csr)
{
    const int e = blockIdx.x * 256 + threadIdx.x;
    if (e < NE) {
        const int src = ei[e];
        const int dst = ei[NE + e];
        csr[atomicAdd(&cursor[dst], 1)] = src;
    }
}

// ---------------------------------------------------------------------------
// Gather: one 64-lane wave per dst node, unroll-4 edge loop for MLP.
// H = relu(H_skip + acc) in place + fused BN stats.
// ---------------------------------------------------------------------------
#define GATHER_BLOCKS 2048
__global__ __launch_bounds__(256) void gather_kernel(
    const int* __restrict__ rowst, const int* __restrict__ csr,
    const float* __restrict__ K, const unsigned int* __restrict__ QVp,
    float* H, float* __restrict__ stats)
{
    const int c  = threadIdx.x & 63;
    const int rg = threadIdx.x >> 6;
    float s = 0.f, s2 = 0.f;

    for (int n = blockIdx.x * 4 + rg; n < NN; n += GATHER_BLOCKS * 4) {
        const float k     = K[(size_t)n * DD + c];
        const float hskip = H[(size_t)n * DD + c];
        const int e0 = rowst[n], e1 = rowst[n + 1];
        float acc = 0.f;
        int i = e0;
        for (; i + 4 <= e1; i += 4) {
            const int s0 = csr[i], s1 = csr[i + 1], s2i = csr[i + 2], s3 = csr[i + 3];
            const unsigned int p0 = QVp[(size_t)s0  * DD + c];
            const unsigned int p1 = QVp[(size_t)s1  * DD + c];
            const unsigned int p2 = QVp[(size_t)s2i * DD + c];
            const unsigned int p3 = QVp[(size_t)s3  * DD + c];
            acc = fmaf(sigmoidf_fast(k + __uint_as_float(p0 << 16)), __uint_as_float(p0 & 0xFFFF0000u), acc);
            acc = fmaf(sigmoidf_fast(k + __uint_as_float(p1 << 16)), __uint_as_float(p1 & 0xFFFF0000u), acc);
            acc = fmaf(sigmoidf_fast(k + __uint_as_float(p2 << 16)), __uint_as_float(p2 & 0xFFFF0000u), acc);
            acc = fmaf(sigmoidf_fast(k + __uint_as_float(p3 << 16)), __uint_as_float(p3 & 0xFFFF0000u), acc);
        }
        for (; i < e1; i++) {
            const unsigned int p0 = QVp[(size_t)csr[i] * DD + c];
            acc = fmaf(sigmoidf_fast(k + __uint_as_float(p0 << 16)), __uint_as_float(p0 & 0xFFFF0000u), acc);
        }
        float o = fmaxf(hskip + acc, 0.f);
        H[(size_t)n * DD + c] = o;
        s += o;
        s2 += o * o;
    }

    __shared__ float ls[256], ls2[256];
    ls[threadIdx.x]  = s;
    ls2[threadIdx.x] = s2;
    __syncthreads();
    if (threadIdx.x < 64) {
        s  = ls[threadIdx.x]  + ls[threadIdx.x + 64]  + ls[threadIdx.x + 128]  + ls[threadIdx.x + 192];
        s2 = ls2[threadIdx.x] + ls2[threadIdx.x + 64] + ls2[threadIdx.x + 128] + ls2[threadIdx.x + 192];
        atomicAdd(&stats[c], s);
        atomicAdd(&stats[64 + c], s2);
    }
}

// ---------------------------------------------------------------------------
// Pooled segment-sum (batch sorted -> run-length accumulate, flush on change).
// ---------------------------------------------------------------------------
#define POOL_ROWS 196
__global__ __launch_bounds__(64) void pool_kernel(
    const float* __restrict__ H, const int* __restrict__ batch,
    float* __restrict__ psum, float* __restrict__ pcnt)
{
    const int c  = threadIdx.x;
    const int r0 = blockIdx.x * POOL_ROWS;
    if (r0 >= NN) return;
    const int r1 = min(r0 + POOL_ROWS, NN);

    int cur = batch[r0];
    float acc = 0.f, cnt = 0.f;
    for (int r = r0; r < r1; r++) {
        const int g = batch[r];
        if (g != cur) {
            atomicAdd(&psum[cur * DD + c], acc);
            if (c == 0) atomicAdd(&pcnt[cur], cnt);
            acc = 0.f; cnt = 0.f; cur = g;
        }
        acc += H[(size_t)r * DD + c];
        cnt += 1.f;
    }
    atomicAdd(&psum[cur * DD + c], acc);
    if (c == 0) atomicAdd(&pcnt[cur], cnt);
}

// ---------------------------------------------------------------------------
// Final: pooled mean -> (folded last-layer BN affine) -> logits -> softmax.
// ---------------------------------------------------------------------------
__global__ __launch_bounds__(256) void final_kernel(
    const float* __restrict__ psum, const float* __restrict__ pcnt,
    const float* __restrict__ stats,
    const float* __restrict__ gamma, const float* __restrict__ beta,
    const float* __restrict__ Wlin, const float* __restrict__ blin,
    float* __restrict__ out)
{
    const int g = blockIdx.x * blockDim.x + threadIdx.x;
    if (g >= NG) return;

    const float invc = 1.0f / fmaxf(pcnt[g], 1.0f);
    const float invN = 1.0f / (float)NN;
    float p[DD];
#pragma unroll
    for (int d = 0; d < DD; d++) {
        const float mean = stats[d] * invN;
        const float var  = stats[64 + d] * invN - mean * mean;
        const float inv  = rsqrtf(var + BN_EPS);
        const float a = inv * gamma[d];
        const float b = beta[d] - mean * a;
        p[d] = fmaf(psum[g * DD + d] * invc, a, b);
    }

    float logits[NC];
    float m = -1e30f;
#pragma unroll
    for (int c = 0; c < NC; c++) {
        float acc = blin[c];
#pragma unroll
        for (int d = 0; d < DD; d++) acc = fmaf(p[d], Wlin[d * NC + c], acc);
        logits[c] = acc;
        m = fmaxf(m, acc);
    }
    float sum = 0.f;
#pragma unroll
    for (int c = 0; c < NC; c++) {
        logits[c] = __expf(logits[c] - m);
        sum += logits[c];
    }
    const float inv = 1.f / sum;
#pragma unroll
    for (int c = 0; c < NC; c++) out[g * NC + c] = logits[c] * inv;
}

// ---------------------------------------------------------------------------
extern "C" void kernel_launch(void* const* d_in, const int* in_sizes, int n_in,
                              void* d_out, int out_size, void* d_ws, size_t ws_size,
                              hipStream_t stream)
{
    const float* X     = (const float*)d_in[0];
    const int*   ei    = (const int*)d_in[1];
    const int*   batch = (const int*)d_in[2];
    const float* Wk    = (const float*)d_in[3];
    const float* Wq    = (const float*)d_in[4];
    const float* Wv    = (const float*)d_in[5];
    const float* Ws    = (const float*)d_in[6];
    const float* bk    = (const float*)d_in[7];
    const float* bq    = (const float*)d_in[8];
    const float* bv    = (const float*)d_in[9];
    const float* bconv = (const float*)d_in[10];
    const float* gamma = (const float*)d_in[11];
    const float* beta  = (const float*)d_in[12];
    const float* Wlin  = (const float*)d_in[13];
    const float* blin  = (const float*)d_in[14];
    float* out = (float*)d_out;

    float* ws = (float*)d_ws;
    const size_t M = (size_t)NN * DD;
    float*        K     = ws;                       // M
    unsigned int* QVp   = (unsigned int*)(K + M);   // M (packed bf16 q|v)
    float*        H     = (float*)(QVp + M);        // M
    // --- contiguous zero-init region ---
    int*   deg   = (int*)(H + M);                   // NN
    float* psum  = (float*)(deg + NN);              // NG*DD
    float* pcnt  = psum + (size_t)NG * DD;          // NG
    float* stats = pcnt + NG;                       // NL*128
    // --- end zero region ---
    int* rowst  = (int*)(stats + NL * 128);         // NN+1
    int* cursor = rowst + NN + 1;                   // NN
    int* psums  = cursor + NN;                      // 256
    int* csr    = psums + 256;                      // NE

    const size_t zero_bytes = (size_t)(NN + NG * DD + NG + NL * 128) * sizeof(float);
    hipMemsetAsync(deg, 0, zero_bytes, stream);

    // ---- CSR build ----
    deg_kernel<<<(NE + 255) / 256, 256, 0, stream>>>(ei, deg);
    scan_partial_kernel<<<NCHUNK, 256, 0, stream>>>(deg, psums);
    scan_offsets_kernel<<<1, 64, 0, stream>>>(psums, rowst);
    scan_final_kernel<<<NCHUNK, 256, 0, stream>>>(deg, psums, rowst, cursor);
    fill_kernel<<<(NE + 255) / 256, 256, 0, stream>>>(ei, cursor, csr);

    // ---- layers (BN folded into next GEMM / final) ----
    const float* hin = X;
    for (int l = 0; l < NL; l++) {
        const float* pS = (l == 0) ? nullptr : stats + (l - 1) * 128;
        const float* pG = (l == 0) ? nullptr : gamma + (l - 1) * 64;
        const float* pB = (l == 0) ? nullptr : beta  + (l - 1) * 64;
        gemm4_kernel<<<(NN + 31) / 32, 256, 0, stream>>>(
            hin, Wk + l * 4096, Wq + l * 4096, Wv + l * 4096, Ws + l * 4096,
            bk + l * 64, bq + l * 64, bv + l * 64, bconv + l * 64,
            pS, pG, pB, K, QVp, H);
        gather_kernel<<<GATHER_BLOCKS, 256, 0, stream>>>(
            rowst, csr, K, QVp, H, stats + l * 128);
        hin = H;
    }

    pool_kernel<<<(NN + POOL_ROWS - 1) / POOL_ROWS, 64, 0, stream>>>(H, batch, psum, pcnt);
    final_kernel<<<1, 256, 0, stream>>>(
        psum, pcnt, stats + 4 * 128, gamma + 4 * 64, beta + 4 * 64, Wlin, blin, out);
}

// Round 5
// 744.527 us; speedup vs baseline: 2.1973x; 2.1973x over previous
//
#include <hip/hip_runtime.h>

#define NN 50000
#define NE 800000
#define DD 64
#define NL 5
#define NG 256
#define NC 10
#define BN_EPS 1e-5f
#define NCHUNK ((NN + 255) / 256)   // 196
#define GROWS 128                    // rows per gemm block
#define GT (GROWS / 16)              // 16-row tiles per block

typedef __attribute__((ext_vector_type(8))) short bf16x8;
typedef __attribute__((ext_vector_type(4))) float f32x4;

// Pack two floats as bf16 (RNE) into one uint: low16 = q, high16 = v.
__device__ inline unsigned int pack_bf16x2(float q, float v) {
    unsigned int uq = __float_as_uint(q);
    unsigned int uv = __float_as_uint(v);
    uq += 0x7FFFu + ((uq >> 16) & 1u);
    uv += 0x7FFFu + ((uv >> 16) & 1u);
    return (uv & 0xFFFF0000u) | (uq >> 16);
}

__device__ inline float sigmoidf_fast(float x) {
    return 1.f / (1.f + __expf(-x));
}

// Split fp32 into bf16 hi (RTZ) + bf16 lo (residual). hi+lo ~ x to ~2^-17.
__device__ inline void split_bf16(float x, short& h, short& l) {
    const unsigned u  = __float_as_uint(x);
    const unsigned hb = u & 0xFFFF0000u;
    h = (short)(hb >> 16);
    const float lo = x - __uint_as_float(hb);
    l = (short)(__float_as_uint(lo) >> 16);
}

// ---------------------------------------------------------------------------
// BN coefficient kernel: a[c], b[c] such that x' = x*a + b. Identity for l=0.
// ---------------------------------------------------------------------------
__global__ void bncoef_kernel(const float* __restrict__ stats,
                              const float* __restrict__ gamma,
                              const float* __restrict__ beta,
                              int useStats, float* __restrict__ ab)
{
    const int c = threadIdx.x;  // 64 threads
    float a = 1.f, b = 0.f;
    if (useStats) {
        const float invN = 1.0f / (float)NN;
        const float mean = stats[c] * invN;
        const float var  = stats[64 + c] * invN - mean * mean;
        const float inv  = rsqrtf(var + BN_EPS);
        a = inv * gamma[c];
        b = beta[c] - mean * a;
    }
    ab[c]      = a;
    ab[64 + c] = b;
}

// ---------------------------------------------------------------------------
// MFMA gemm4: K/Q/V/S = BN(Hin) @ W* + b*. Split-bf16 x split-bf16, 3 MFMAs
// per 16x16x32 product -> fp32-equivalent precision, fp32 accumulate.
// Wave w handles column tile [w*16, w*16+16) of ALL 4 matrices (so Q,V pack
// locally). No LDS; W fragments held in VGPRs across the M loop.
// NOT in-place: Hin != OUT (ping-pong buffers).
// Verified layouts (learn_hip m89/m91/m120): A[m=lane&15][k=quad*8+j],
// B[k=quad*8+j][n=lane&15], C/D col=lane&15, row=quad*4+reg.
// ---------------------------------------------------------------------------
__global__ __launch_bounds__(256) void gemm4_mfma(
    const float* __restrict__ Hin,
    const float* __restrict__ Wk, const float* __restrict__ Wq,
    const float* __restrict__ Wv, const float* __restrict__ Ws,
    const float* __restrict__ bk, const float* __restrict__ bq,
    const float* __restrict__ bv, const float* __restrict__ bs,
    const float* __restrict__ ab,   // 128: a[64], b[64]
    float* __restrict__ K, unsigned int* __restrict__ QVp,
    float* __restrict__ OUT)
{
    const int wave = threadIdx.x >> 6;    // ntile 0..3
    const int lane = threadIdx.x & 63;
    const int n15  = lane & 15;
    const int g    = lane >> 4;           // quad
    const int col  = wave * 16 + n15;

    // ---- W fragments (held across M loop): [mat][chunk], hi+lo ----
    const float* Wm[4] = {Wk, Wq, Wv, Ws};
    bf16x8 wh[4][2], wl[4][2];
#pragma unroll
    for (int m = 0; m < 4; m++) {
#pragma unroll
        for (int c = 0; c < 2; c++) {
            bf16x8 h, l;
#pragma unroll
            for (int j = 0; j < 8; j++) {
                const int k = g * 8 + j + 32 * c;
                short hs, ls;
                split_bf16(Wm[m][k * DD + col], hs, ls);
                h[j] = hs; l[j] = ls;
            }
            wh[m][c] = h; wl[m][c] = l;
        }
    }

    // ---- BN coefficients for this lane's k indices ----
    float ac[2][8], bc[2][8];
#pragma unroll
    for (int c = 0; c < 2; c++)
#pragma unroll
        for (int j = 0; j < 8; j++) {
            const int k = g * 8 + j + 32 * c;
            ac[c][j] = ab[k];
            bc[c][j] = ab[64 + k];
        }

    const float bkc = bk[col], bqc = bq[col], bvc = bv[col], bsc = bs[col];

    const int rowbase0 = blockIdx.x * GROWS;
#pragma unroll 1
    for (int t = 0; t < GT; t++) {
        const int rowbase = rowbase0 + t * 16;
        if (rowbase >= NN) break;   // NN % 16 == 0, so tiles are all-or-nothing

        const float* rp = Hin + (size_t)(rowbase + n15) * DD;
        const float4 x0 = *(const float4*)(rp + g * 8);
        const float4 x1 = *(const float4*)(rp + g * 8 + 4);
        const float4 x2 = *(const float4*)(rp + g * 8 + 32);
        const float4 x3 = *(const float4*)(rp + g * 8 + 36);

        bf16x8 ah[2], al[2];
        {
            const float v0[8] = {x0.x, x0.y, x0.z, x0.w, x1.x, x1.y, x1.z, x1.w};
            const float v1[8] = {x2.x, x2.y, x2.z, x2.w, x3.x, x3.y, x3.z, x3.w};
            bf16x8 h0, l0, h1, l1;
#pragma unroll
            for (int j = 0; j < 8; j++) {
                short hs, ls;
                split_bf16(fmaf(v0[j], ac[0][j], bc[0][j]), hs, ls);
                h0[j] = hs; l0[j] = ls;
                split_bf16(fmaf(v1[j], ac[1][j], bc[1][j]), hs, ls);
                h1[j] = hs; l1[j] = ls;
            }
            ah[0] = h0; al[0] = l0; ah[1] = h1; al[1] = l1;
        }

        f32x4 acc[4];
#pragma unroll
        for (int m = 0; m < 4; m++) acc[m] = (f32x4){0.f, 0.f, 0.f, 0.f};

#pragma unroll
        for (int c = 0; c < 2; c++) {
#pragma unroll
            for (int m = 0; m < 4; m++) {
                acc[m] = __builtin_amdgcn_mfma_f32_16x16x32_bf16(ah[c], wh[m][c], acc[m], 0, 0, 0);
                acc[m] = __builtin_amdgcn_mfma_f32_16x16x32_bf16(al[c], wh[m][c], acc[m], 0, 0, 0);
                acc[m] = __builtin_amdgcn_mfma_f32_16x16x32_bf16(ah[c], wl[m][c], acc[m], 0, 0, 0);
            }
        }

#pragma unroll
        for (int r = 0; r < 4; r++) {
            const int row = rowbase + g * 4 + r;
            const size_t o = (size_t)row * DD + col;
            K[o]   = acc[0][r] + bkc;
            QVp[o] = pack_bf16x2(acc[1][r] + bqc, acc[2][r] + bvc);
            OUT[o] = acc[3][r] + bsc;
        }
    }
}

// ---------------------------------------------------------------------------
// CSR build: histogram of dst, two-level exclusive scan, scatter fill.
// ---------------------------------------------------------------------------
__global__ __launch_bounds__(256) void deg_kernel(
    const int* __restrict__ ei, int* __restrict__ deg)
{
    const int e = blockIdx.x * 256 + threadIdx.x;
    if (e < NE) atomicAdd(&deg[ei[NE + e]], 1);
}

__global__ __launch_bounds__(256) void scan_partial_kernel(
    const int* __restrict__ deg, int* __restrict__ psums)
{
    __shared__ int ls[256];
    const int i = blockIdx.x * 256 + threadIdx.x;
    ls[threadIdx.x] = (i < NN) ? deg[i] : 0;
    __syncthreads();
    for (int off = 128; off > 0; off >>= 1) {
        if (threadIdx.x < off) ls[threadIdx.x] += ls[threadIdx.x + off];
        __syncthreads();
    }
    if (threadIdx.x == 0) psums[blockIdx.x] = ls[0];
}

__global__ void scan_offsets_kernel(int* __restrict__ psums, int* __restrict__ rowst)
{
    if (threadIdx.x == 0) {
        int running = 0;
        for (int i = 0; i < NCHUNK; i++) {
            int t = psums[i];
            psums[i] = running;
            running += t;
        }
        rowst[NN] = running;  // == NE
    }
}

__global__ __launch_bounds__(256) void scan_final_kernel(
    const int* __restrict__ deg, const int* __restrict__ psums,
    int* __restrict__ rowst, int* __restrict__ cursor)
{
    __shared__ int ls[256];
    const int i = blockIdx.x * 256 + threadIdx.x;
    const int x = (i < NN) ? deg[i] : 0;
    ls[threadIdx.x] = x;
    __syncthreads();
    for (int off = 1; off < 256; off <<= 1) {
        int v = (threadIdx.x >= off) ? ls[threadIdx.x - off] : 0;
        __syncthreads();
        ls[threadIdx.x] += v;
        __syncthreads();
    }
    if (i < NN) {
        const int excl = psums[blockIdx.x] + ls[threadIdx.x] - x;
        rowst[i]  = excl;
        cursor[i] = excl;
    }
}

__global__ __launch_bounds__(256) void fill_kernel(
    const int* __restrict__ ei, int* __restrict__ cursor, int* __restrict__ csr)
{
    const int e = blockIdx.x * 256 + threadIdx.x;
    if (e < NE) {
        const int src = ei[e];
        const int dst = ei[NE + e];
        csr[atomicAdd(&cursor[dst], 1)] = src;
    }
}

// ---------------------------------------------------------------------------
// Gather: one 64-lane wave per dst node, unroll-4 edge loop for MLP.
// H = relu(H_skip + acc) in place + fused BN stats.
// ---------------------------------------------------------------------------
#define GATHER_BLOCKS 2048
__global__ __launch_bounds__(256) void gather_kernel(
    const int* __restrict__ rowst, const int* __restrict__ csr,
    const float* __restrict__ K, const unsigned int* __restrict__ QVp,
    float* H, float* __restrict__ stats)
{
    const int c  = threadIdx.x & 63;
    const int rg = threadIdx.x >> 6;
    float s = 0.f, s2 = 0.f;

    for (int n = blockIdx.x * 4 + rg; n < NN; n += GATHER_BLOCKS * 4) {
        const float k     = K[(size_t)n * DD + c];
        const float hskip = H[(size_t)n * DD + c];
        const int e0 = rowst[n], e1 = rowst[n + 1];
        float acc = 0.f;
        int i = e0;
        for (; i + 4 <= e1; i += 4) {
            const int s0 = csr[i], s1 = csr[i + 1], s2i = csr[i + 2], s3 = csr[i + 3];
            const unsigned int p0 = QVp[(size_t)s0  * DD + c];
            const unsigned int p1 = QVp[(size_t)s1  * DD + c];
            const unsigned int p2 = QVp[(size_t)s2i * DD + c];
            const unsigned int p3 = QVp[(size_t)s3  * DD + c];
            acc = fmaf(sigmoidf_fast(k + __uint_as_float(p0 << 16)), __uint_as_float(p0 & 0xFFFF0000u), acc);
            acc = fmaf(sigmoidf_fast(k + __uint_as_float(p1 << 16)), __uint_as_float(p1 & 0xFFFF0000u), acc);
            acc = fmaf(sigmoidf_fast(k + __uint_as_float(p2 << 16)), __uint_as_float(p2 & 0xFFFF0000u), acc);
            acc = fmaf(sigmoidf_fast(k + __uint_as_float(p3 << 16)), __uint_as_float(p3 & 0xFFFF0000u), acc);
        }
        for (; i < e1; i++) {
            const unsigned int p0 = QVp[(size_t)csr[i] * DD + c];
            acc = fmaf(sigmoidf_fast(k + __uint_as_float(p0 << 16)), __uint_as_float(p0 & 0xFFFF0000u), acc);
        }
        float o = fmaxf(hskip + acc, 0.f);
        H[(size_t)n * DD + c] = o;
        s += o;
        s2 += o * o;
    }

    __shared__ float ls[256], ls2[256];
    ls[threadIdx.x]  = s;
    ls2[threadIdx.x] = s2;
    __syncthreads();
    if (threadIdx.x < 64) {
        s  = ls[threadIdx.x]  + ls[threadIdx.x + 64]  + ls[threadIdx.x + 128]  + ls[threadIdx.x + 192];
        s2 = ls2[threadIdx.x] + ls2[threadIdx.x + 64] + ls2[threadIdx.x + 128] + ls2[threadIdx.x + 192];
        atomicAdd(&stats[c], s);
        atomicAdd(&stats[64 + c], s2);
    }
}

// ---------------------------------------------------------------------------
// Pooled segment-sum (batch sorted -> run-length accumulate, flush on change).
// ---------------------------------------------------------------------------
#define POOL_ROWS 196
__global__ __launch_bounds__(64) void pool_kernel(
    const float* __restrict__ H, const int* __restrict__ batch,
    float* __restrict__ psum, float* __restrict__ pcnt)
{
    const int c  = threadIdx.x;
    const int r0 = blockIdx.x * POOL_ROWS;
    if (r0 >= NN) return;
    const int r1 = min(r0 + POOL_ROWS, NN);

    int cur = batch[r0];
    float acc = 0.f, cnt = 0.f;
    for (int r = r0; r < r1; r++) {
        const int g = batch[r];
        if (g != cur) {
            atomicAdd(&psum[cur * DD + c], acc);
            if (c == 0) atomicAdd(&pcnt[cur], cnt);
            acc = 0.f; cnt = 0.f; cur = g;
        }
        acc += H[(size_t)r * DD + c];
        cnt += 1.f;
    }
    atomicAdd(&psum[cur * DD + c], acc);
    if (c == 0) atomicAdd(&pcnt[cur], cnt);
}

// ---------------------------------------------------------------------------
// Final: pooled mean -> (folded last-layer BN affine) -> logits -> softmax.
// ---------------------------------------------------------------------------
__global__ __launch_bounds__(256) void final_kernel(
    const float* __restrict__ psum, const float* __restrict__ pcnt,
    const float* __restrict__ stats,
    const float* __restrict__ gamma, const float* __restrict__ beta,
    const float* __restrict__ Wlin, const float* __restrict__ blin,
    float* __restrict__ out)
{
    const int g = blockIdx.x * blockDim.x + threadIdx.x;
    if (g >= NG) return;

    const float invc = 1.0f / fmaxf(pcnt[g], 1.0f);
    const float invN = 1.0f / (float)NN;
    float p[DD];
#pragma unroll
    for (int d = 0; d < DD; d++) {
        const float mean = stats[d] * invN;
        const float var  = stats[64 + d] * invN - mean * mean;
        const float inv  = rsqrtf(var + BN_EPS);
        const float a = inv * gamma[d];
        const float b = beta[d] - mean * a;
        p[d] = fmaf(psum[g * DD + d] * invc, a, b);
    }

    float logits[NC];
    float m = -1e30f;
#pragma unroll
    for (int c = 0; c < NC; c++) {
        float acc = blin[c];
#pragma unroll
        for (int d = 0; d < DD; d++) acc = fmaf(p[d], Wlin[d * NC + c], acc);
        logits[c] = acc;
        m = fmaxf(m, acc);
    }
    float sum = 0.f;
#pragma unroll
    for (int c = 0; c < NC; c++) {
        logits[c] = __expf(logits[c] - m);
        sum += logits[c];
    }
    const float inv = 1.f / sum;
#pragma unroll
    for (int c = 0; c < NC; c++) out[g * NC + c] = logits[c] * inv;
}

// ---------------------------------------------------------------------------
extern "C" void kernel_launch(void* const* d_in, const int* in_sizes, int n_in,
                              void* d_out, int out_size, void* d_ws, size_t ws_size,
                              hipStream_t stream)
{
    const float* X     = (const float*)d_in[0];
    const int*   ei    = (const int*)d_in[1];
    const int*   batch = (const int*)d_in[2];
    const float* Wk    = (const float*)d_in[3];
    const float* Wq    = (const float*)d_in[4];
    const float* Wv    = (const float*)d_in[5];
    const float* Ws    = (const float*)d_in[6];
    const float* bk    = (const float*)d_in[7];
    const float* bq    = (const float*)d_in[8];
    const float* bv    = (const float*)d_in[9];
    const float* bconv = (const float*)d_in[10];
    const float* gamma = (const float*)d_in[11];
    const float* beta  = (const float*)d_in[12];
    const float* Wlin  = (const float*)d_in[13];
    const float* blin  = (const float*)d_in[14];
    float* out = (float*)d_out;

    float* ws = (float*)d_ws;
    const size_t M = (size_t)NN * DD;
    float*        K     = ws;                       // M
    unsigned int* QVp   = (unsigned int*)(K + M);   // M (packed bf16 q|v)
    float*        H0    = (float*)(QVp + M);        // M
    float*        H1    = H0 + M;                   // M (gemm ping-pong)
    // --- contiguous zero-init region ---
    int*   deg   = (int*)(H1 + M);                  // NN
    float* psum  = (float*)(deg + NN);              // NG*DD
    float* pcnt  = psum + (size_t)NG * DD;          // NG
    float* stats = pcnt + NG;                       // NL*128
    // --- end zero region ---
    float* bnab  = stats + NL * 128;                // 128
    int* rowst  = (int*)(bnab + 128);               // NN+1
    int* cursor = rowst + NN + 1;                   // NN
    int* psums  = cursor + NN;                      // 256
    int* csr    = psums + 256;                      // NE

    const size_t zero_bytes = (size_t)(NN + NG * DD + NG + NL * 128) * sizeof(float);
    hipMemsetAsync(deg, 0, zero_bytes, stream);

    // ---- CSR build ----
    deg_kernel<<<(NE + 255) / 256, 256, 0, stream>>>(ei, deg);
    scan_partial_kernel<<<NCHUNK, 256, 0, stream>>>(deg, psums);
    scan_offsets_kernel<<<1, 64, 0, stream>>>(psums, rowst);
    scan_final_kernel<<<NCHUNK, 256, 0, stream>>>(deg, psums, rowst, cursor);
    fill_kernel<<<(NE + 255) / 256, 256, 0, stream>>>(ei, cursor, csr);

    // ---- layers (BN folded into next GEMM / final) ----
    const float* hin = X;
    for (int l = 0; l < NL; l++) {
        float* hout = (l & 1) ? H1 : H0;
        bncoef_kernel<<<1, 64, 0, stream>>>(
            stats + (l ? (l - 1) * 128 : 0),
            gamma + (l ? (l - 1) * 64 : 0),
            beta  + (l ? (l - 1) * 64 : 0),
            l ? 1 : 0, bnab);
        gemm4_mfma<<<(NN + GROWS - 1) / GROWS, 256, 0, stream>>>(
            hin, Wk + l * 4096, Wq + l * 4096, Wv + l * 4096, Ws + l * 4096,
            bk + l * 64, bq + l * 64, bv + l * 64, bconv + l * 64,
            bnab, K, QVp, hout);
        gather_kernel<<<GATHER_BLOCKS, 256, 0, stream>>>(
            rowst, csr, K, QVp, hout, stats + l * 128);
        hin = hout;
    }

    pool_kernel<<<(NN + POOL_ROWS - 1) / POOL_ROWS, 64, 0, stream>>>(hin, batch, psum, pcnt);
    final_kernel<<<1, 256, 0, stream>>>(
        psum, pcnt, stats + 4 * 128, gamma + 4 * 64, beta + 4 * 64, Wlin, blin, out);
}

// Round 6
// 721.363 us; speedup vs baseline: 2.2678x; 1.0321x over previous
//
#include <hip/hip_runtime.h>

#define NN 50000
#define NE 800000
#define DD 64
#define NL 5
#define NG 256
#define NC 10
#define BN_EPS 1e-5f
#define NCHUNK ((NN + 255) / 256)   // 196
#define GROWS 128                    // rows per gemm block
#define GT (GROWS / 16)              // 16-row tiles per block
#define SAW 68                       // staged-A row stride (uints): 2-way conflicts only

typedef __attribute__((ext_vector_type(8))) short bf16x8;
typedef __attribute__((ext_vector_type(4))) float f32x4;

// Pack two floats as bf16 (RNE) into one uint: low16 = q, high16 = v.
__device__ inline unsigned int pack_bf16x2(float q, float v) {
    unsigned int uq = __float_as_uint(q);
    unsigned int uv = __float_as_uint(v);
    uq += 0x7FFFu + ((uq >> 16) & 1u);
    uv += 0x7FFFu + ((uv >> 16) & 1u);
    return (uv & 0xFFFF0000u) | (uq >> 16);
}

__device__ inline float sigmoidf_fast(float x) {
    return 1.f / (1.f + __expf(-x));
}

// Split fp32 into bf16 hi (RTZ) + bf16 lo (residual). hi+lo ~ x to ~2^-17.
__device__ inline void split_bf16(float x, short& h, short& l) {
    const unsigned u  = __float_as_uint(x);
    const unsigned hb = u & 0xFFFF0000u;
    h = (short)(hb >> 16);
    const float lo = x - __uint_as_float(hb);
    l = (short)(__float_as_uint(lo) >> 16);
}

// gate-fma for one packed bf16 q|v edge value
__device__ inline float gate_fma(float k, unsigned p, float acc) {
    const float q = __uint_as_float(p << 16);
    const float v = __uint_as_float(p & 0xFFFF0000u);
    return fmaf(sigmoidf_fast(k + q), v, acc);
}

// ---------------------------------------------------------------------------
// MFMA gemm4: K/Q/V/S = BN(Hin) @ W* + b*. Split-bf16 x split-bf16, 3 MFMAs
// per 16x16x32 product -> fp32-equivalent precision, fp32 accumulate.
// BN-affine of the PREVIOUS layer folded in (computed per block, no extra
// dispatch). A-tile (128 rows) staged ONCE per block in LDS as packed
// (hi<<16|lo) split-bf16, row stride SAW=68 -> only free 2-way conflicts.
// Wave w owns column tile [w*16, w*16+16) of all 4 output matrices.
// NOT in-place: Hin != OUT (ping-pong).
// Layouts (learn_hip m89/m91): A[m=lane&15][k=quad*8+j],
// B[k=quad*8+j][n=lane&15], C/D col=lane&15, row=quad*4+reg.
// ---------------------------------------------------------------------------
__global__ __launch_bounds__(256) void gemm4_mfma(
    const float* __restrict__ Hin,
    const float* __restrict__ Wk, const float* __restrict__ Wq,
    const float* __restrict__ Wv, const float* __restrict__ Ws,
    const float* __restrict__ bk, const float* __restrict__ bq,
    const float* __restrict__ bv, const float* __restrict__ bs,
    const float* __restrict__ prevStats,   // null for layer 0
    const float* __restrict__ prevGamma, const float* __restrict__ prevBeta,
    float* __restrict__ K, unsigned int* __restrict__ QVp,
    float* __restrict__ OUT)
{
    __shared__ unsigned int sA[GROWS * SAW];   // 34 KB packed split-bf16 A
    __shared__ float sAB[128];                 // a[64], b[64]
    const int tid = threadIdx.x;

    // ---- BN affine coefficients (folded bncoef) ----
    if (tid < 64) {
        float a = 1.f, b = 0.f;
        if (prevStats) {
            const float invN = 1.0f / (float)NN;
            const float mean = prevStats[tid] * invN;
            const float var  = prevStats[64 + tid] * invN - mean * mean;
            const float inv  = rsqrtf(var + BN_EPS);
            a = inv * prevGamma[tid];
            b = prevBeta[tid] - mean * a;
        }
        sAB[tid]      = a;
        sAB[64 + tid] = b;
    }
    __syncthreads();

    // ---- stage A: affine + split + pack, once per block ----
    const int row0 = blockIdx.x * GROWS;
    for (int i = tid; i < GROWS * 16; i += 256) {
        const int row = i >> 4;
        const int k4  = (i & 15) * 4;
        float4 x = make_float4(0.f, 0.f, 0.f, 0.f);
        if (row0 + row < NN)
            x = *(const float4*)(Hin + (size_t)(row0 + row) * DD + k4);
        const float xs[4] = {x.x, x.y, x.z, x.w};
        unsigned int* dst = &sA[row * SAW + k4];
#pragma unroll
        for (int j = 0; j < 4; j++) {
            const float xv = fmaf(xs[j], sAB[k4 + j], sAB[64 + k4 + j]);
            short hs, ls;
            split_bf16(xv, hs, ls);
            dst[j] = ((unsigned int)(unsigned short)hs << 16) | (unsigned short)ls;
        }
    }

    const int wave = tid >> 6;    // column tile 0..3
    const int lane = tid & 63;
    const int n15  = lane & 15;
    const int g    = lane >> 4;   // quad
    const int col  = wave * 16 + n15;

    // ---- W fragments (held across tile loop): [mat][k-chunk], hi+lo ----
    const float* Wm[4] = {Wk, Wq, Wv, Ws};
    bf16x8 wh[4][2], wl[4][2];
#pragma unroll
    for (int m = 0; m < 4; m++) {
#pragma unroll
        for (int c = 0; c < 2; c++) {
            bf16x8 h, l;
#pragma unroll
            for (int j = 0; j < 8; j++) {
                const int k = g * 8 + j + 32 * c;
                short hs, ls;
                split_bf16(Wm[m][k * DD + col], hs, ls);
                h[j] = hs; l[j] = ls;
            }
            wh[m][c] = h; wl[m][c] = l;
        }
    }

    const float bkc = bk[col], bqc = bq[col], bvc = bv[col], bsc = bs[col];
    __syncthreads();

#pragma unroll 1
    for (int t = 0; t < GT; t++) {
        const int rowbase = row0 + t * 16;
        if (rowbase >= NN) break;   // NN % 16 == 0: tiles are all-or-nothing

        // A fragments from LDS: row n15, k = g*8+j (+32c), unpack hi/lo
        bf16x8 ah[2], al[2];
#pragma unroll
        for (int c = 0; c < 2; c++) {
            const uint4 u0 = *(const uint4*)&sA[(t * 16 + n15) * SAW + g * 8 + 32 * c];
            const uint4 u1 = *(const uint4*)&sA[(t * 16 + n15) * SAW + g * 8 + 32 * c + 4];
            const unsigned int us[8] = {u0.x, u0.y, u0.z, u0.w, u1.x, u1.y, u1.z, u1.w};
            bf16x8 h, l;
#pragma unroll
            for (int j = 0; j < 8; j++) {
                h[j] = (short)(us[j] >> 16);
                l[j] = (short)(us[j] & 0xFFFFu);
            }
            ah[c] = h; al[c] = l;
        }

        f32x4 acc[4];
#pragma unroll
        for (int m = 0; m < 4; m++) acc[m] = (f32x4){0.f, 0.f, 0.f, 0.f};

#pragma unroll
        for (int c = 0; c < 2; c++) {
#pragma unroll
            for (int m = 0; m < 4; m++) {
                acc[m] = __builtin_amdgcn_mfma_f32_16x16x32_bf16(ah[c], wh[m][c], acc[m], 0, 0, 0);
                acc[m] = __builtin_amdgcn_mfma_f32_16x16x32_bf16(al[c], wh[m][c], acc[m], 0, 0, 0);
                acc[m] = __builtin_amdgcn_mfma_f32_16x16x32_bf16(ah[c], wl[m][c], acc[m], 0, 0, 0);
            }
        }

#pragma unroll
        for (int r = 0; r < 4; r++) {
            const int row = rowbase + g * 4 + r;
            const size_t o = (size_t)row * DD + col;
            K[o]   = acc[0][r] + bkc;
            QVp[o] = pack_bf16x2(acc[1][r] + bqc, acc[2][r] + bvc);
            OUT[o] = acc[3][r] + bsc;
        }
    }
}

// ---------------------------------------------------------------------------
// CSR build: histogram of dst, two-level exclusive scan, scatter fill.
// ---------------------------------------------------------------------------
__global__ __launch_bounds__(256) void deg_kernel(
    const int* __restrict__ ei, int* __restrict__ deg)
{
    const int e = blockIdx.x * 256 + threadIdx.x;
    if (e < NE) atomicAdd(&deg[ei[NE + e]], 1);
}

__global__ __launch_bounds__(256) void scan_partial_kernel(
    const int* __restrict__ deg, int* __restrict__ psums)
{
    __shared__ int ls[256];
    const int i = blockIdx.x * 256 + threadIdx.x;
    ls[threadIdx.x] = (i < NN) ? deg[i] : 0;
    __syncthreads();
    for (int off = 128; off > 0; off >>= 1) {
        if (threadIdx.x < off) ls[threadIdx.x] += ls[threadIdx.x + off];
        __syncthreads();
    }
    if (threadIdx.x == 0) psums[blockIdx.x] = ls[0];
}

__global__ void scan_offsets_kernel(int* __restrict__ psums, int* __restrict__ rowst)
{
    if (threadIdx.x == 0) {
        int running = 0;
        for (int i = 0; i < NCHUNK; i++) {
            int t = psums[i];
            psums[i] = running;
            running += t;
        }
        rowst[NN] = running;  // == NE
    }
}

__global__ __launch_bounds__(256) void scan_final_kernel(
    const int* __restrict__ deg, const int* __restrict__ psums,
    int* __restrict__ rowst, int* __restrict__ cursor)
{
    __shared__ int ls[256];
    const int i = blockIdx.x * 256 + threadIdx.x;
    const int x = (i < NN) ? deg[i] : 0;
    ls[threadIdx.x] = x;
    __syncthreads();
    for (int off = 1; off < 256; off <<= 1) {
        int v = (threadIdx.x >= off) ? ls[threadIdx.x - off] : 0;
        __syncthreads();
        ls[threadIdx.x] += v;
        __syncthreads();
    }
    if (i < NN) {
        const int excl = psums[blockIdx.x] + ls[threadIdx.x] - x;
        rowst[i]  = excl;
        cursor[i] = excl;
    }
}

__global__ __launch_bounds__(256) void fill_kernel(
    const int* __restrict__ ei, int* __restrict__ cursor, int* __restrict__ csr)
{
    const int e = blockIdx.x * 256 + threadIdx.x;
    if (e < NE) {
        const int src = ei[e];
        const int dst = ei[NE + e];
        csr[atomicAdd(&cursor[dst], 1)] = src;
    }
}

// ---------------------------------------------------------------------------
// Gather: one 64-lane wave per TWO dst nodes, interleaved unroll-4 edge
// loops -> 8 independent QVp loads in flight. H = relu(H_skip + acc) in
// place + fused BN stats.
// ---------------------------------------------------------------------------
#define GATHER_BLOCKS 2048
__global__ __launch_bounds__(256) void gather_kernel(
    const int* __restrict__ rowst, const int* __restrict__ csr,
    const float* __restrict__ K, const unsigned int* __restrict__ QVp,
    float* H, float* __restrict__ stats)
{
    const int c  = threadIdx.x & 63;
    const int wv = threadIdx.x >> 6;
    const int gw = blockIdx.x * 4 + wv;   // global wave id
    float s = 0.f, s2 = 0.f;

    for (int n0 = gw * 2; n0 < NN; n0 += GATHER_BLOCKS * 4 * 2) {
        const int n1 = n0 + 1;            // NN even -> always valid
        const float k0 = K[(size_t)n0 * DD + c];
        const float k1 = K[(size_t)n1 * DD + c];
        const float h0 = H[(size_t)n0 * DD + c];
        const float h1 = H[(size_t)n1 * DD + c];
        const int e00 = rowst[n0], e01 = rowst[n1], e11 = rowst[n1 + 1];

        float acc0 = 0.f, acc1 = 0.f;
        int i0 = e00, i1 = e01;

        while (i0 + 4 <= e01 && i1 + 4 <= e11) {
            const int a0 = csr[i0], a1 = csr[i0 + 1], a2 = csr[i0 + 2], a3 = csr[i0 + 3];
            const int b0 = csr[i1], b1 = csr[i1 + 1], b2 = csr[i1 + 2], b3 = csr[i1 + 3];
            const unsigned pa0 = QVp[(size_t)a0 * DD + c];
            const unsigned pa1 = QVp[(size_t)a1 * DD + c];
            const unsigned pa2 = QVp[(size_t)a2 * DD + c];
            const unsigned pa3 = QVp[(size_t)a3 * DD + c];
            const unsigned pb0 = QVp[(size_t)b0 * DD + c];
            const unsigned pb1 = QVp[(size_t)b1 * DD + c];
            const unsigned pb2 = QVp[(size_t)b2 * DD + c];
            const unsigned pb3 = QVp[(size_t)b3 * DD + c];
            acc0 = gate_fma(k0, pa0, acc0);
            acc0 = gate_fma(k0, pa1, acc0);
            acc0 = gate_fma(k0, pa2, acc0);
            acc0 = gate_fma(k0, pa3, acc0);
            acc1 = gate_fma(k1, pb0, acc1);
            acc1 = gate_fma(k1, pb1, acc1);
            acc1 = gate_fma(k1, pb2, acc1);
            acc1 = gate_fma(k1, pb3, acc1);
            i0 += 4; i1 += 4;
        }
        while (i0 + 4 <= e01) {
            const int a0 = csr[i0], a1 = csr[i0 + 1], a2 = csr[i0 + 2], a3 = csr[i0 + 3];
            const unsigned pa0 = QVp[(size_t)a0 * DD + c];
            const unsigned pa1 = QVp[(size_t)a1 * DD + c];
            const unsigned pa2 = QVp[(size_t)a2 * DD + c];
            const unsigned pa3 = QVp[(size_t)a3 * DD + c];
            acc0 = gate_fma(k0, pa0, acc0);
            acc0 = gate_fma(k0, pa1, acc0);
            acc0 = gate_fma(k0, pa2, acc0);
            acc0 = gate_fma(k0, pa3, acc0);
            i0 += 4;
        }
        while (i1 + 4 <= e11) {
            const int b0 = csr[i1], b1 = csr[i1 + 1], b2 = csr[i1 + 2], b3 = csr[i1 + 3];
            const unsigned pb0 = QVp[(size_t)b0 * DD + c];
            const unsigned pb1 = QVp[(size_t)b1 * DD + c];
            const unsigned pb2 = QVp[(size_t)b2 * DD + c];
            const unsigned pb3 = QVp[(size_t)b3 * DD + c];
            acc1 = gate_fma(k1, pb0, acc1);
            acc1 = gate_fma(k1, pb1, acc1);
            acc1 = gate_fma(k1, pb2, acc1);
            acc1 = gate_fma(k1, pb3, acc1);
            i1 += 4;
        }
        for (; i0 < e01; i0++) acc0 = gate_fma(k0, QVp[(size_t)csr[i0] * DD + c], acc0);
        for (; i1 < e11; i1++) acc1 = gate_fma(k1, QVp[(size_t)csr[i1] * DD + c], acc1);

        const float o0 = fmaxf(h0 + acc0, 0.f);
        const float o1 = fmaxf(h1 + acc1, 0.f);
        H[(size_t)n0 * DD + c] = o0;
        H[(size_t)n1 * DD + c] = o1;
        s += o0 + o1;
        s2 += o0 * o0 + o1 * o1;
    }

    __shared__ float ls[256], ls2[256];
    ls[threadIdx.x]  = s;
    ls2[threadIdx.x] = s2;
    __syncthreads();
    if (threadIdx.x < 64) {
        s  = ls[threadIdx.x]  + ls[threadIdx.x + 64]  + ls[threadIdx.x + 128]  + ls[threadIdx.x + 192];
        s2 = ls2[threadIdx.x] + ls2[threadIdx.x + 64] + ls2[threadIdx.x + 128] + ls2[threadIdx.x + 192];
        atomicAdd(&stats[c], s);
        atomicAdd(&stats[64 + c], s2);
    }
}

// ---------------------------------------------------------------------------
// Pooled segment-sum (batch sorted -> run-length accumulate, flush on change).
// ---------------------------------------------------------------------------
#define POOL_ROWS 196
__global__ __launch_bounds__(64) void pool_kernel(
    const float* __restrict__ H, const int* __restrict__ batch,
    float* __restrict__ psum, float* __restrict__ pcnt)
{
    const int c  = threadIdx.x;
    const int r0 = blockIdx.x * POOL_ROWS;
    if (r0 >= NN) return;
    const int r1 = min(r0 + POOL_ROWS, NN);

    int cur = batch[r0];
    float acc = 0.f, cnt = 0.f;
    for (int r = r0; r < r1; r++) {
        const int g = batch[r];
        if (g != cur) {
            atomicAdd(&psum[cur * DD + c], acc);
            if (c == 0) atomicAdd(&pcnt[cur], cnt);
            acc = 0.f; cnt = 0.f; cur = g;
        }
        acc += H[(size_t)r * DD + c];
        cnt += 1.f;
    }
    atomicAdd(&psum[cur * DD + c], acc);
    if (c == 0) atomicAdd(&pcnt[cur], cnt);
}

// ---------------------------------------------------------------------------
// Final: pooled mean -> (folded last-layer BN affine) -> logits -> softmax.
// ---------------------------------------------------------------------------
__global__ __launch_bounds__(256) void final_kernel(
    const float* __restrict__ psum, const float* __restrict__ pcnt,
    const float* __restrict__ stats,
    const float* __restrict__ gamma, const float* __restrict__ beta,
    const float* __restrict__ Wlin, const float* __restrict__ blin,
    float* __restrict__ out)
{
    const int g = blockIdx.x * blockDim.x + threadIdx.x;
    if (g >= NG) return;

    const float invc = 1.0f / fmaxf(pcnt[g], 1.0f);
    const float invN = 1.0f / (float)NN;
    float p[DD];
#pragma unroll
    for (int d = 0; d < DD; d++) {
        const float mean = stats[d] * invN;
        const float var  = stats[64 + d] * invN - mean * mean;
        const float inv  = rsqrtf(var + BN_EPS);
        const float a = inv * gamma[d];
        const float b = beta[d] - mean * a;
        p[d] = fmaf(psum[g * DD + d] * invc, a, b);
    }

    float logits[NC];
    float m = -1e30f;
#pragma unroll
    for (int c = 0; c < NC; c++) {
        float acc = blin[c];
#pragma unroll
        for (int d = 0; d < DD; d++) acc = fmaf(p[d], Wlin[d * NC + c], acc);
        logits[c] = acc;
        m = fmaxf(m, acc);
    }
    float sum = 0.f;
#pragma unroll
    for (int c = 0; c < NC; c++) {
        logits[c] = __expf(logits[c] - m);
        sum += logits[c];
    }
    const float inv = 1.f / sum;
#pragma unroll
    for (int c = 0; c < NC; c++) out[g * NC + c] = logits[c] * inv;
}

// ---------------------------------------------------------------------------
extern "C" void kernel_launch(void* const* d_in, const int* in_sizes, int n_in,
                              void* d_out, int out_size, void* d_ws, size_t ws_size,
                              hipStream_t stream)
{
    const float* X     = (const float*)d_in[0];
    const int*   ei    = (const int*)d_in[1];
    const int*   batch = (const int*)d_in[2];
    const float* Wk    = (const float*)d_in[3];
    const float* Wq    = (const float*)d_in[4];
    const float* Wv    = (const float*)d_in[5];
    const float* Ws    = (const float*)d_in[6];
    const float* bk    = (const float*)d_in[7];
    const float* bq    = (const float*)d_in[8];
    const float* bv    = (const float*)d_in[9];
    const float* bconv = (const float*)d_in[10];
    const float* gamma = (const float*)d_in[11];
    const float* beta  = (const float*)d_in[12];
    const float* Wlin  = (const float*)d_in[13];
    const float* blin  = (const float*)d_in[14];
    float* out = (float*)d_out;

    float* ws = (float*)d_ws;
    const size_t M = (size_t)NN * DD;
    float*        K     = ws;                       // M
    unsigned int* QVp   = (unsigned int*)(K + M);   // M (packed bf16 q|v)
    float*        H0    = (float*)(QVp + M);        // M
    float*        H1    = H0 + M;                   // M (gemm ping-pong)
    // --- contiguous zero-init region ---
    int*   deg   = (int*)(H1 + M);                  // NN
    float* psum  = (float*)(deg + NN);              // NG*DD
    float* pcnt  = psum + (size_t)NG * DD;          // NG
    float* stats = pcnt + NG;                       // NL*128
    // --- end zero region ---
    int* rowst  = (int*)(stats + NL * 128);         // NN+1
    int* cursor = rowst + NN + 1;                   // NN
    int* psums  = cursor + NN;                      // 256
    int* csr    = psums + 256;                      // NE

    const size_t zero_bytes = (size_t)(NN + NG * DD + NG + NL * 128) * sizeof(float);
    hipMemsetAsync(deg, 0, zero_bytes, stream);

    // ---- CSR build ----
    deg_kernel<<<(NE + 255) / 256, 256, 0, stream>>>(ei, deg);
    scan_partial_kernel<<<NCHUNK, 256, 0, stream>>>(deg, psums);
    scan_offsets_kernel<<<1, 64, 0, stream>>>(psums, rowst);
    scan_final_kernel<<<NCHUNK, 256, 0, stream>>>(deg, psums, rowst, cursor);
    fill_kernel<<<(NE + 255) / 256, 256, 0, stream>>>(ei, cursor, csr);

    // ---- layers (BN folded into next GEMM / final) ----
    const float* hin = X;
    for (int l = 0; l < NL; l++) {
        float* hout = (l & 1) ? H1 : H0;
        const float* pS = l ? stats + (l - 1) * 128 : nullptr;
        const float* pG = l ? gamma + (l - 1) * 64  : nullptr;
        const float* pB = l ? beta  + (l - 1) * 64  : nullptr;
        gemm4_mfma<<<(NN + GROWS - 1) / GROWS, 256, 0, stream>>>(
            hin, Wk + l * 4096, Wq + l * 4096, Wv + l * 4096, Ws + l * 4096,
            bk + l * 64, bq + l * 64, bv + l * 64, bconv + l * 64,
            pS, pG, pB, K, QVp, hout);
        gather_kernel<<<GATHER_BLOCKS, 256, 0, stream>>>(
            rowst, csr, K, QVp, hout, stats + l * 128);
        hin = hout;
    }

    pool_kernel<<<(NN + POOL_ROWS - 1) / POOL_ROWS, 64, 0, stream>>>(hin, batch, psum, pcnt);
    final_kernel<<<1, 256, 0, stream>>>(
        psum, pcnt, stats + 4 * 128, gamma + 4 * 64, beta + 4 * 64, Wlin, blin, out);
}